// Round 12
// baseline (1419.238 us; speedup 1.0000x reference)
//
#include <hip/hip_runtime.h>

#define DIM 200
#define NENT 100000
#define NEDGE 1000000
#define EHALF 500000
#define NB 1024
#define NFILT 200
#define FLATSZ 39200

#define NDF ((size_t)NENT * DIM)
#define REGF ((size_t)20100000)
#define WPLANE (208 * 224)

typedef float floatx4 __attribute__((ext_vector_type(4)));
typedef short bf16x8 __attribute__((ext_vector_type(8)));
typedef short bf16x4 __attribute__((ext_vector_type(4)));
typedef _Float16 halfx8 __attribute__((ext_vector_type(8)));
typedef _Float16 halfx4 __attribute__((ext_vector_type(4)));

__device__ __forceinline__ void gAtomicAdd(float* p, float v) { unsafeAtomicAdd(p, v); }
__device__ __forceinline__ void gAtomicAdd(double* p, double v) { unsafeAtomicAdd(p, v); }

__device__ __forceinline__ short f2bf(float f) {
    union { float f; unsigned u; } v; v.f = f;
    unsigned r = v.u + 0x7fffu + ((v.u >> 16) & 1u);
    return (short)(r >> 16);
}
__device__ __forceinline__ float bf2f(short s) {
    union { float f; unsigned u; } v; v.u = ((unsigned)(unsigned short)s) << 16;
    return v.f;
}
__device__ __forceinline__ void split8(const floatx4& lo4, const floatx4& hi4,
                                       bf16x8& h, bf16x8& l) {
#pragma unroll
    for (int e = 0; e < 4; ++e) {
        short hh = f2bf(lo4[e]); h[e] = hh; l[e] = f2bf(lo4[e] - bf2f(hh));
        short hh2 = f2bf(hi4[e]); h[e + 4] = hh2; l[e + 4] = f2bf(hi4[e] - bf2f(hh2));
    }
}

// ---------------------------------------------------------------- CSR build
__global__ __launch_bounds__(256) void edge_hist(
    const int* __restrict__ dst, int* __restrict__ hist)
{
    int stride = gridDim.x * blockDim.x;
    for (int e = blockIdx.x * 256 + threadIdx.x; e < NEDGE; e += stride)
        atomicAdd(&hist[dst[e]], 1);
}

__global__ __launch_bounds__(256) void scan1(
    const int* __restrict__ hist, int* __restrict__ incl, int* __restrict__ bsum)
{
    __shared__ int sm[256];
    int i = blockIdx.x * 256 + threadIdx.x;
    int t = threadIdx.x;
    sm[t] = (i < NENT) ? hist[i] : 0;
    __syncthreads();
    for (int off = 1; off < 256; off <<= 1) {
        int v = (t >= off) ? sm[t - off] : 0;
        __syncthreads();
        sm[t] += v;
        __syncthreads();
    }
    if (i < NENT) incl[i] = sm[t];
    if (t == 255) bsum[blockIdx.x] = sm[255];
}

__global__ __launch_bounds__(512) void scan2(int* bsum, int nb)
{
    __shared__ int sm[512];
    int t = threadIdx.x;
    int v = (t < nb) ? bsum[t] : 0;
    sm[t] = v;
    __syncthreads();
    for (int off = 1; off < 512; off <<= 1) {
        int u = (t >= off) ? sm[t - off] : 0;
        __syncthreads();
        sm[t] += u;
        __syncthreads();
    }
    if (t < nb) bsum[t] = sm[t] - v;
}

__global__ __launch_bounds__(256) void scan3(
    const int* __restrict__ hist, int* __restrict__ offs,
    const int* __restrict__ bsum, int* __restrict__ cursor)
{
    int i = blockIdx.x * 256 + threadIdx.x;
    if (i < NENT) {
        int excl = offs[i] - hist[i] + bsum[blockIdx.x];
        offs[i] = excl;
        cursor[i] = excl;
    }
    if (i == 0) offs[NENT] = NEDGE;
}

__global__ __launch_bounds__(256) void edge_fill(
    const int* __restrict__ src, const int* __restrict__ dst,
    const int* __restrict__ etype, const float* __restrict__ enorm,
    int* __restrict__ cursor, int4* __restrict__ recs)
{
    int stride = gridDim.x * blockDim.x;
    for (int e = blockIdx.x * 256 + threadIdx.x; e < NEDGE; e += stride) {
        int pos = atomicAdd(&cursor[dst[e]], 1);
        recs[pos] = make_int4(src[e], etype[e] | ((e >= EHALF) ? 0x10000 : 0),
                              __float_as_int(enorm[e]), 0);
    }
}

__global__ __launch_bounds__(256) void build_map(
    const int* __restrict__ subj, const int* __restrict__ obj, int* __restrict__ map)
{
    int i = blockIdx.x * 256 + threadIdx.x;
    if (i < NB) map[subj[i]] = i;
    else if (i < 2 * NB) map[obj[i - NB]] = i;
}

// ---------------------------------------------------------------- gather -> bf16 hi/lo planes
// XBF=0: x from fp32 xf (exact). XBF=1: x from BOTH planes hi+lo (~fp32, 2^-17 rel).
template<int XBF>
__global__ __launch_bounds__(256) void gather_nodes(
    const float* __restrict__ xf, const short* __restrict__ xh,
    const short* __restrict__ xl, const float* __restrict__ r,
    const int* __restrict__ offs, const int4* __restrict__ recs,
    short* __restrict__ aggIh, short* __restrict__ aggIl,
    short* __restrict__ aggOh, short* __restrict__ aggOl)
{
    int node = blockIdx.x * 4 + (threadIdx.x >> 6);
    int lane = threadIdx.x & 63;
    if (node >= NENT) return;
    int beg = offs[node], end = offs[node + 1];
    bool act = lane < 50;
    int lane_c = min(lane, 49);
    const float4* rb = (const float4*)r;
    float4 aI = make_float4(0.f, 0.f, 0.f, 0.f);
    float4 aO = make_float4(0.f, 0.f, 0.f, 0.f);

    auto ld_x = [&](int s) -> float4 {
        if (XBF) {
            bf16x4 vh = *(const bf16x4*)&xh[(size_t)s * 200 + lane_c * 4];
            bf16x4 vl = *(const bf16x4*)&xl[(size_t)s * 200 + lane_c * 4];
            return make_float4(bf2f(vh[0]) + bf2f(vl[0]), bf2f(vh[1]) + bf2f(vl[1]),
                               bf2f(vh[2]) + bf2f(vl[2]), bf2f(vh[3]) + bf2f(vl[3]));
        } else {
            return ((const float4*)xf)[(size_t)s * 50 + lane_c];
        }
    };

    if (beg < end) {
        int i1 = min(beg + 1, end - 1);
        int4 rcA = recs[beg];
        int4 rcB = recs[i1];
        float4 xvA = ld_x(rcA.x);
        float4 rvA = rb[(size_t)(rcA.y & 0xffff) * 50 + lane_c];
        for (int i = beg; i < end; ++i) {
            int i2 = min(i + 2, end - 1);
            int4 rcC = recs[i2];
            float4 xvB = ld_x(rcB.x);
            float4 rvB = rb[(size_t)(rcB.y & 0xffff) * 50 + lane_c];
            float w = __int_as_float(rcA.z);
            float wI = (rcA.y & 0x10000) ? 0.f : w;
            float wO = w - wI;
            float px = xvA.x * rvA.x, py = xvA.y * rvA.y,
                  pz = xvA.z * rvA.z, pw = xvA.w * rvA.w;
            aI.x += px * wI; aI.y += py * wI; aI.z += pz * wI; aI.w += pw * wI;
            aO.x += px * wO; aO.y += py * wO; aO.z += pz * wO; aO.w += pw * wO;
            rcA = rcB; rcB = rcC; xvA = xvB; rvA = rvB;
        }
    }
    if (act) {
        size_t off4 = (size_t)node * 200 + lane * 4;
        bf16x4 h, l;
        h[0] = f2bf(aI.x); l[0] = f2bf(aI.x - bf2f(h[0]));
        h[1] = f2bf(aI.y); l[1] = f2bf(aI.y - bf2f(h[1]));
        h[2] = f2bf(aI.z); l[2] = f2bf(aI.z - bf2f(h[2]));
        h[3] = f2bf(aI.w); l[3] = f2bf(aI.w - bf2f(h[3]));
        *(bf16x4*)&aggIh[off4] = h;
        *(bf16x4*)&aggIl[off4] = l;
        h[0] = f2bf(aO.x); l[0] = f2bf(aO.x - bf2f(h[0]));
        h[1] = f2bf(aO.y); l[1] = f2bf(aO.y - bf2f(h[1]));
        h[2] = f2bf(aO.z); l[2] = f2bf(aO.z - bf2f(h[2]));
        h[3] = f2bf(aO.w); l[3] = f2bf(aO.w - bf2f(h[3]));
        *(bf16x4*)&aggOh[off4] = h;
        *(bf16x4*)&aggOl[off4] = l;
    }
}

// ---------------------------------------------------------------- weight packing
__global__ __launch_bounds__(256) void pack_w3(
    const float* __restrict__ w0, const float* __restrict__ w1,
    const float* __restrict__ w2, const float* __restrict__ lrel,
    short* __restrict__ Wp)
{
    int i = blockIdx.x * 256 + threadIdx.x;
    if (i >= 3 * WPLANE) return;
    int seg = i / WPLANE, rem = i % WPLANE;
    int n = rem / 224, k = rem % 224;
    const float* W = (seg == 0) ? w0 : (seg == 1) ? w1 : w2;
    float v = (n < 200 && k < 200) ? W[k * 200 + n] : 0.f;
    if (seg == 2 && n < 200 && k < 200) v *= lrel[k];
    short hi = f2bf(v);
    Wp[i] = hi;
    Wp[i + 3 * WPLANE] = f2bf(v - bf2f(hi));
}

__global__ __launch_bounds__(256) void pack_fcw(
    const float* __restrict__ W, _Float16* __restrict__ Wt)
{
    long i = (long)blockIdx.x * 256 + threadIdx.x;
    if (i >= (long)208 * FLATSZ) return;
    int n = (int)(i / FLATSZ);
    Wt[i] = (n < 200) ? (_Float16)W[i] : (_Float16)0.f;
}

// ---------------------------------------------------------------- split-bf16 MFMA GEMM
// Double-buffered B staging: one barrier per k-chunk; next chunk's B global-loads
// issued before the MFMAs (they hide the L2 latency), ds_write after.
template<int NF0, int NF, bool A2F32>
__device__ __forceinline__ void gemm_body(
    const short* __restrict__ A0h, const short* __restrict__ A0l,
    const short* __restrict__ A1h, const short* __restrict__ A1l,
    const float* __restrict__ A2f,
    const short* __restrict__ A2h, const short* __restrict__ A2l,
    const short* __restrict__ WpH, const short* __restrict__ WpL,
    float* C, const float* __restrict__ bias, const int* __restrict__ map,
    float alpha, int M, double* __restrict__ s1, double* __restrict__ s2,
    short* BsH, short* BsL, float* fsum, float* fsq)
{
    int t = threadIdx.x;
    int lane = t & 63, wave = t >> 6;
    int col16 = lane & 15, quad = lane >> 4;
    int row_base = blockIdx.x * 128 + wave * 32;
    if (t < 112) { fsum[t] = 0.f; fsq[t] = 0.f; }
    floatx4 acc[NF][2];
#pragma unroll
    for (int nf = 0; nf < NF; ++nf) { acc[nf][0] = (floatx4)0.f; acc[nf][1] = (floatx4)0.f; }
    int r0 = row_base + col16, r1 = row_base + 16 + col16;
    int r0c = min(r0, M - 1), r1c = min(r1, M - 1);
    constexpr int rows4 = NF * 16 * 4;     // 16B-chunks per plane per chunk
    constexpr int SI = (rows4 + 255) / 256; // staging iters (2)

    bf16x8 sH[SI], sL[SI];
    auto stage_issue = [&](int kc) {
        int seg = kc / 7, c = kc - seg * 7, k0 = c * 32;
        const short* WH = WpH + seg * WPLANE;
        const short* WL = WpL + seg * WPLANE;
#pragma unroll
        for (int it = 0; it < SI; ++it) {
            int i = t + it * 256;
            if (i < rows4) {
                int nl = i >> 2, part = i & 3;
                int n = NF0 * 16 + nl;
                sH[it] = *(const bf16x8*)&WH[n * 224 + k0 + part * 8];
                sL[it] = *(const bf16x8*)&WL[n * 224 + k0 + part * 8];
            }
        }
    };
    auto stage_write = [&](int buf) {
        short* dH = BsH + buf * (112 * 40);
        short* dL = BsL + buf * (112 * 40);
#pragma unroll
        for (int it = 0; it < SI; ++it) {
            int i = t + it * 256;
            if (i < rows4) {
                int nl = i >> 2, part = i & 3;
                *(bf16x8*)&dH[nl * 40 + part * 8] = sH[it];
                *(bf16x8*)&dL[nl * 40 + part * 8] = sL[it];
            }
        }
    };

    stage_issue(0);
    stage_write(0);
    __syncthreads();

    for (int kc = 0; kc < 21; ++kc) {
        int seg = kc / 7, c = kc - seg * 7, k0 = c * 32;
        int buf = kc & 1;
        if (kc < 20) stage_issue(kc + 1);           // global loads in flight
        int koff = k0 + quad * 8;
        bf16x8 a0h, a0l, a1h, a1l;
        if (koff < 200) {
            size_t o0 = (size_t)r0c * 200 + koff, o1 = (size_t)r1c * 200 + koff;
            if (seg == 0) {
                a0h = *(const bf16x8*)&A0h[o0]; a0l = *(const bf16x8*)&A0l[o0];
                a1h = *(const bf16x8*)&A0h[o1]; a1l = *(const bf16x8*)&A0l[o1];
            } else if (seg == 1) {
                a0h = *(const bf16x8*)&A1h[o0]; a0l = *(const bf16x8*)&A1l[o0];
                a1h = *(const bf16x8*)&A1h[o1]; a1l = *(const bf16x8*)&A1l[o1];
            } else if (A2F32) {
                floatx4 l0 = *(const floatx4*)&A2f[o0];
                floatx4 h0 = *(const floatx4*)&A2f[o0 + 4];
                floatx4 l1 = *(const floatx4*)&A2f[o1];
                floatx4 h1 = *(const floatx4*)&A2f[o1 + 4];
                split8(l0, h0, a0h, a0l);
                split8(l1, h1, a1h, a1l);
            } else {
                a0h = *(const bf16x8*)&A2h[o0]; a0l = *(const bf16x8*)&A2l[o0];
                a1h = *(const bf16x8*)&A2h[o1]; a1l = *(const bf16x8*)&A2l[o1];
            }
        } else {
            a0h = (bf16x8)0; a0l = (bf16x8)0; a1h = (bf16x8)0; a1l = (bf16x8)0;
        }
        const short* rH = BsH + buf * (112 * 40);
        const short* rL = BsL + buf * (112 * 40);
#pragma unroll
        for (int nf = 0; nf < NF; ++nf) {
            bf16x8 bh = *(const bf16x8*)&rH[(nf * 16 + col16) * 40 + quad * 8];
            bf16x8 bl = *(const bf16x8*)&rL[(nf * 16 + col16) * 40 + quad * 8];
            acc[nf][0] = __builtin_amdgcn_mfma_f32_16x16x32_bf16(a0h, bh, acc[nf][0], 0, 0, 0);
            acc[nf][0] = __builtin_amdgcn_mfma_f32_16x16x32_bf16(a0h, bl, acc[nf][0], 0, 0, 0);
            acc[nf][0] = __builtin_amdgcn_mfma_f32_16x16x32_bf16(a0l, bh, acc[nf][0], 0, 0, 0);
            acc[nf][1] = __builtin_amdgcn_mfma_f32_16x16x32_bf16(a1h, bh, acc[nf][1], 0, 0, 0);
            acc[nf][1] = __builtin_amdgcn_mfma_f32_16x16x32_bf16(a1h, bl, acc[nf][1], 0, 0, 0);
            acc[nf][1] = __builtin_amdgcn_mfma_f32_16x16x32_bf16(a1l, bh, acc[nf][1], 0, 0, 0);
        }
        if (kc < 20) stage_write(buf ^ 1);
        __syncthreads();
    }
    int slot[2][4];
    if (map) {
#pragma unroll
        for (int h = 0; h < 2; ++h)
#pragma unroll
            for (int j = 0; j < 4; ++j) {
                int rr = row_base + h * 16 + quad * 4 + j;
                slot[h][j] = (rr < M) ? map[rr] : -1;
            }
    }
#pragma unroll
    for (int nf = 0; nf < NF; ++nf) {
        int lc = nf * 16 + col16;
        int colg = NF0 * 16 + lc;
        if (colg >= 200) continue;
        float bv = bias[colg];
        float ls = 0.f, lq = 0.f;
#pragma unroll
        for (int h = 0; h < 2; ++h) {
            int rbase = row_base + h * 16 + quad * 4;
#pragma unroll
            for (int j = 0; j < 4; ++j) {
                int rr = rbase + j;
                if (rr < M) {
                    float v = acc[nf][h][j] * alpha + bv;
                    ls += v; lq += v * v;
                    if (!map) {
                        C[(size_t)rr * 200 + colg] = v;
                    } else {
                        int s = slot[h][j];
                        if (s >= 0) C[(size_t)s * 200 + colg] = v;
                    }
                }
            }
        }
        ls += __shfl_down(ls, 32); ls += __shfl_down(ls, 16);
        lq += __shfl_down(lq, 32); lq += __shfl_down(lq, 16);
        if (quad == 0) {
            atomicAdd(&fsum[lc], ls);
            atomicAdd(&fsq[lc], lq);
        }
    }
    __syncthreads();
    if (t < NF * 16) {
        int colg = NF0 * 16 + t;
        if (colg < 200) {
            gAtomicAdd(&s1[colg], (double)fsum[t]);
            gAtomicAdd(&s2[colg], (double)fsq[t]);
        }
    }
}

template<bool A2F32>
__global__ __launch_bounds__(256) void gemm_mfma(
    const short* A0h, const short* A0l, const short* A1h, const short* A1l,
    const float* A2f, const short* A2h, const short* A2l,
    const short* __restrict__ WpH, const short* __restrict__ WpL,
    float* C, const float* __restrict__ bias, const int* __restrict__ map,
    float alpha, int M, double* __restrict__ s1, double* __restrict__ s2)
{
    __shared__ short BsH[2 * 112 * 40];
    __shared__ short BsL[2 * 112 * 40];
    __shared__ float fsum[112];
    __shared__ float fsq[112];
    if (blockIdx.y == 0)
        gemm_body<0, 7, A2F32>(A0h, A0l, A1h, A1l, A2f, A2h, A2l, WpH, WpL,
                               C, bias, map, alpha, M, s1, s2, BsH, BsL, fsum, fsq);
    else
        gemm_body<7, 6, A2F32>(A0h, A0l, A1h, A1l, A2f, A2h, A2l, WpH, WpL,
                               C, bias, map, alpha, M, s1, s2, BsH, BsL, fsum, fsq);
}

// ---------------------------------------------------------------- fc MFMA GEMM body (fp16)
template<int NF0, int NF>
__device__ __forceinline__ void fc_gemm_body(
    const _Float16* __restrict__ Ph, const _Float16* __restrict__ Wt,
    float* __restrict__ part, int ky, _Float16* Bs)
{
    int t = threadIdx.x;
    int lane = t & 63, wave = t >> 6;
    int col16 = lane & 15, quad = lane >> 4;
    int row_base = blockIdx.x * 128 + wave * 32;
    int c0 = ky * 25;
    floatx4 acc[NF][2];
#pragma unroll
    for (int nf = 0; nf < NF; ++nf) { acc[nf][0] = (floatx4)0.f; acc[nf][1] = (floatx4)0.f; }
    int r0 = row_base + col16, r1 = row_base + 16 + col16;
    const int rows4 = NF * 16 * 4;

    for (int c = c0; c < c0 + 25; ++c) {
        int k0 = c * 32;
        for (int i = t; i < rows4; i += 256) {
            int nl = i >> 2, part_i = i & 3;
            int n = NF0 * 16 + nl;
            *(halfx8*)&Bs[nl * 40 + part_i * 8] =
                *(const halfx8*)&Wt[(size_t)n * FLATSZ + k0 + part_i * 8];
        }
        __syncthreads();
        int koff = k0 + quad * 8;
        halfx8 a0 = *(const halfx8*)&Ph[(size_t)r0 * FLATSZ + koff];
        halfx8 a1 = *(const halfx8*)&Ph[(size_t)r1 * FLATSZ + koff];
#pragma unroll
        for (int nf = 0; nf < NF; ++nf) {
            halfx8 b = *(const halfx8*)&Bs[(nf * 16 + col16) * 40 + quad * 8];
            acc[nf][0] = __builtin_amdgcn_mfma_f32_16x16x32_f16(a0, b, acc[nf][0], 0, 0, 0);
            acc[nf][1] = __builtin_amdgcn_mfma_f32_16x16x32_f16(a1, b, acc[nf][1], 0, 0, 0);
        }
        __syncthreads();
    }
    float* out = part + (size_t)ky * (NB * 200);
#pragma unroll
    for (int nf = 0; nf < NF; ++nf) {
        int colg = NF0 * 16 + nf * 16 + col16;
        if (colg >= 200) continue;
#pragma unroll
        for (int h = 0; h < 2; ++h) {
            int rbase = row_base + h * 16 + quad * 4;
#pragma unroll
            for (int j = 0; j < 4; ++j)
                out[(size_t)(rbase + j) * 200 + colg] = acc[nf][h][j];
        }
    }
}

__global__ __launch_bounds__(256) void fc_gemm(
    const _Float16* __restrict__ Ph, const _Float16* __restrict__ Wt,
    float* __restrict__ part)
{
    __shared__ _Float16 Bs[112 * 40];
    int ky = blockIdx.y >> 1;
    if ((blockIdx.y & 1) == 0)
        fc_gemm_body<0, 7>(Ph, Wt, part, ky, Bs);
    else
        fc_gemm_body<7, 6>(Ph, Wt, part, ky, Bs);
}

__global__ __launch_bounds__(256) void fc_reduce(
    const float* __restrict__ part, const float* __restrict__ bias,
    float* __restrict__ hfc)
{
    int i = blockIdx.x * 256 + threadIdx.x;
    float acc = bias[i % 200];
#pragma unroll
    for (int y = 0; y < 49; ++y) acc += part[(size_t)y * (NB * 200) + i];
    hfc[i] = acc;
}

// ---------------------------------------------------------------- stats / bn
__global__ __launch_bounds__(256) void colstats(
    const float* __restrict__ X, int M, int rpb,
    double* __restrict__ s1, double* __restrict__ s2)
{
    int c = threadIdx.x;
    if (c >= 200) return;
    int r0 = blockIdx.x * rpb;
    int r1 = min(r0 + rpb, M);
    float sum = 0.f, sq = 0.f;
    for (int rr = r0; rr < r1; ++rr) {
        float v = X[(size_t)rr * 200 + c];
        sum += v; sq += v * v;
    }
    gAtomicAdd(&s1[c], (double)sum);
    gAtomicAdd(&s2[c], (double)sq);
}

__global__ void finalize_stats(const double* __restrict__ s1, const double* __restrict__ s2,
                               const float* __restrict__ g, const float* __restrict__ bb,
                               float* __restrict__ sc, float* __restrict__ sh,
                               int ncols, double count)
{
    int c = threadIdx.x;
    if (c >= ncols) return;
    double m = s1[c] / count;
    double v = s2[c] / count - m * m;
    double scd = (double)g[c] / sqrt(v + 1e-5);
    sc[c] = (float)scd;
    sh[c] = (float)((double)bb[c] - m * scd);
}

__global__ __launch_bounds__(256) void bn_tanh_split(
    const float* __restrict__ X, const float* __restrict__ sc,
    const float* __restrict__ sh, short* __restrict__ Xh, short* __restrict__ Xl,
    long n4)
{
    long stride = (long)gridDim.x * blockDim.x;
    for (long i = (long)blockIdx.x * blockDim.x + threadIdx.x; i < n4; i += stride) {
        int c4 = (int)(i % 50) * 4;
        float4 v = ((const float4*)X)[i];
        float a0 = tanhf(v.x * sc[c4 + 0] + sh[c4 + 0]);
        float a1 = tanhf(v.y * sc[c4 + 1] + sh[c4 + 1]);
        float a2 = tanhf(v.z * sc[c4 + 2] + sh[c4 + 2]);
        float a3 = tanhf(v.w * sc[c4 + 3] + sh[c4 + 3]);
        bf16x4 h, l;
        h[0] = f2bf(a0); l[0] = f2bf(a0 - bf2f(h[0]));
        h[1] = f2bf(a1); l[1] = f2bf(a1 - bf2f(h[1]));
        h[2] = f2bf(a2); l[2] = f2bf(a2 - bf2f(h[2]));
        h[3] = f2bf(a3); l[3] = f2bf(a3 - bf2f(h[3]));
        *(bf16x4*)&Xh[i * 4] = h;
        *(bf16x4*)&Xl[i * 4] = l;
    }
}

__global__ __launch_bounds__(256) void bn_act_200(
    float* __restrict__ X, const float* __restrict__ sc, const float* __restrict__ sh,
    long n4, int act)
{
    long stride = (long)gridDim.x * blockDim.x;
    for (long i = (long)blockIdx.x * blockDim.x + threadIdx.x; i < n4; i += stride) {
        int c4 = (int)(i % 50) * 4;
        float4 v = ((const float4*)X)[i];
        float a0 = v.x * sc[c4 + 0] + sh[c4 + 0];
        float a1 = v.y * sc[c4 + 1] + sh[c4 + 1];
        float a2 = v.z * sc[c4 + 2] + sh[c4 + 2];
        float a3 = v.w * sc[c4 + 3] + sh[c4 + 3];
        if (act == 0) { a0 = tanhf(a0); a1 = tanhf(a1); a2 = tanhf(a2); a3 = tanhf(a3); }
        else { a0 = fmaxf(a0, 0.f); a1 = fmaxf(a1, 0.f); a2 = fmaxf(a2, 0.f); a3 = fmaxf(a3, 0.f); }
        ((float4*)X)[i] = make_float4(a0, a1, a2, a3);
    }
}

__global__ __launch_bounds__(256) void rel_mm(
    const float* __restrict__ R, const float* __restrict__ W, float* __restrict__ O)
{
    int idx = blockIdx.x * blockDim.x + threadIdx.x;
    if (idx >= 200 * 200) return;
    int row = idx / 200, col = idx - row * 200;
    float acc = 0.f;
    for (int k = 0; k < 200; ++k) acc = fmaf(R[row * 200 + k], W[k * 200 + col], acc);
    O[idx] = acc;
}

__global__ __launch_bounds__(256) void build_stk(
    const float* __restrict__ x2c, const float* __restrict__ r2,
    const int* __restrict__ subj, const int* __restrict__ ridx,
    const int* __restrict__ map,
    float* __restrict__ stk, double* __restrict__ s1, double* __restrict__ s2)
{
    __shared__ float wsum[4], wsq[4];
    int b = blockIdx.x, t = threadIdx.x;
    const float* se = x2c + (size_t)map[subj[b]] * DIM;
    const float* re = r2 + (size_t)ridx[b] * DIM;
    float sum = 0.f, sq = 0.f;
    for (int i = t; i < 400; i += 256) {
        float v = (i < 200) ? se[i] : re[i - 200];
        stk[(size_t)b * 400 + i] = v;
        sum += v; sq += v * v;
    }
    for (int off = 32; off > 0; off >>= 1) {
        sum += __shfl_down(sum, off);
        sq  += __shfl_down(sq, off);
    }
    if ((t & 63) == 0) { wsum[t >> 6] = sum; wsq[t >> 6] = sq; }
    __syncthreads();
    if (t == 0) {
        float S = wsum[0] + wsum[1] + wsum[2] + wsum[3];
        float Q = wsq[0] + wsq[1] + wsq[2] + wsq[3];
        gAtomicAdd(&s1[0], (double)S);
        gAtomicAdd(&s2[0], (double)Q);
    }
}

__global__ __launch_bounds__(256) void conv_fwd(
    const float* __restrict__ stk, const float* __restrict__ conv_w,
    const float* __restrict__ conv_b, const float* __restrict__ sc0,
    const float* __restrict__ sh0, _Float16* __restrict__ Ph,
    double* __restrict__ s1, double* __restrict__ s2)
{
    __shared__ float img[400];
    __shared__ float wsm[9800];
    __shared__ float bsm[200];
    __shared__ float fsum[200];
    __shared__ float fsq[200];
    int b = blockIdx.x, t = threadIdx.x;
    float scale0 = sc0[0], shift0 = sh0[0];
    if (t < 200) { fsum[t] = 0.f; fsq[t] = 0.f; bsm[t] = conv_b[t]; }
    for (int i = t; i < 400; i += 256) img[i] = stk[(size_t)b * 400 + i] * scale0 + shift0;
    for (int i = t; i < 9800; i += 256) wsm[i] = conv_w[i];
    __syncthreads();
    for (int fy = t; fy < 2800; fy += 256) {
        int f = fy / 14, y = fy - (fy / 14) * 14;
        const float* wf = &wsm[f * 49];
        float acc[14];
        float bias = bsm[f];
#pragma unroll
        for (int xx = 0; xx < 14; ++xx) acc[xx] = bias;
#pragma unroll
        for (int i = 0; i < 7; ++i) {
            const float* rowp = &img[(y + i) * 20];
            float rv[20];
#pragma unroll
            for (int c = 0; c < 20; ++c) rv[c] = rowp[c];
#pragma unroll
            for (int j = 0; j < 7; ++j) {
                float wv = wf[i * 7 + j];
#pragma unroll
                for (int xx = 0; xx < 14; ++xx) acc[xx] = fmaf(rv[xx + j], wv, acc[xx]);
            }
        }
        float ls = 0.f, lq = 0.f;
        _Float16* pp = Ph + (size_t)b * FLATSZ + (size_t)f * 196 + y * 14;
#pragma unroll
        for (int xx = 0; xx < 14; ++xx) {
            float v = acc[xx];
            pp[xx] = (_Float16)v;
            ls += v; lq += v * v;
        }
        atomicAdd(&fsum[f], ls);
        atomicAdd(&fsq[f], lq);
    }
    __syncthreads();
    if (t < 200) {
        gAtomicAdd(&s1[t], (double)fsum[t]);
        gAtomicAdd(&s2[t], (double)fsq[t]);
    }
}

__global__ __launch_bounds__(256) void bn1_relu_f16(
    _Float16* __restrict__ Ph, const float* __restrict__ sc, const float* __restrict__ sh)
{
    long n4 = (long)NB * (FLATSZ / 4);
    long stride = (long)gridDim.x * blockDim.x;
    for (long i = (long)blockIdx.x * blockDim.x + threadIdx.x; i < n4; i += stride) {
        int k4 = (int)(i % (FLATSZ / 4));
        int f = k4 / 49;
        float s = sc[f], h = sh[f];
        halfx4 v = ((const halfx4*)Ph)[i];
#pragma unroll
        for (int e = 0; e < 4; ++e) {
            float x = (float)v[e];
            x = fmaxf(x * s + h, 0.f);
            v[e] = (_Float16)x;
        }
        ((halfx4*)Ph)[i] = v;
    }
}

__global__ __launch_bounds__(256) void score_mm(
    const float* __restrict__ Hn, const float* __restrict__ x2c,
    const int* __restrict__ obj, const int* __restrict__ map,
    float* __restrict__ out)
{
    __shared__ float Asm[16][17];
    __shared__ float Bsm[16][17];
    int tx = threadIdx.x & 15, ty = threadIdx.x >> 4;
    int row = blockIdx.y * 16 + ty;
    int col = blockIdx.x * 16 + tx;
    int oj = map[obj[blockIdx.x * 16 + ty]];
    float acc = 0.f;
    for (int k0 = 0; k0 < 200; k0 += 16) {
        int k = k0 + tx;
        Asm[ty][tx] = (k < 200) ? Hn[(size_t)row * 200 + k] : 0.f;
        Bsm[ty][tx] = (k < 200) ? x2c[(size_t)oj * 200 + k] : 0.f;
        __syncthreads();
#pragma unroll
        for (int kk = 0; kk < 16; ++kk) acc = fmaf(Asm[ty][kk], Bsm[tx][kk], acc);
        __syncthreads();
    }
    out[(size_t)row * NB + col] = 1.f / (1.f + expf(-acc));
}

// ---------------------------------------------------------------- driver
extern "C" void kernel_launch(void* const* d_in, const int* in_sizes, int n_in,
                              void* d_out, int out_size, void* d_ws, size_t ws_size,
                              hipStream_t stream)
{
    (void)in_sizes; (void)n_in; (void)out_size;
    const float* init_embed = (const float*)d_in[0];
    const float* init_rel   = (const float*)d_in[1];
    const float* edge_norm  = (const float*)d_in[2];
    const float* w_in1  = (const float*)d_in[3];
    const float* w_out1 = (const float*)d_in[4];
    const float* w_loop1= (const float*)d_in[5];
    const float* w_rel1 = (const float*)d_in[6];
    const float* lrel1  = (const float*)d_in[7];
    const float* b1     = (const float*)d_in[8];
    const float* gm1    = (const float*)d_in[9];
    const float* be1    = (const float*)d_in[10];
    const float* w_in2  = (const float*)d_in[11];
    const float* w_out2 = (const float*)d_in[12];
    const float* w_loop2= (const float*)d_in[13];
    const float* w_rel2 = (const float*)d_in[14];
    const float* lrel2  = (const float*)d_in[15];
    const float* b2     = (const float*)d_in[16];
    const float* gm2    = (const float*)d_in[17];
    const float* be2    = (const float*)d_in[18];
    const float* conv_w = (const float*)d_in[19];
    const float* conv_b = (const float*)d_in[20];
    const float* fc_w   = (const float*)d_in[21];
    const float* fc_b   = (const float*)d_in[22];
    const float* bn0_g  = (const float*)d_in[23];
    const float* bn0_b  = (const float*)d_in[24];
    const float* bn1_g  = (const float*)d_in[25];
    const float* bn1_b  = (const float*)d_in[26];
    const float* bn2_g  = (const float*)d_in[27];
    const float* bn2_b  = (const float*)d_in[28];
    const int* subj   = (const int*)d_in[29];
    const int* relidx = (const int*)d_in[30];
    const int* obj    = (const int*)d_in[31];
    const int* src    = (const int*)d_in[32];
    const int* dst    = (const int*)d_in[33];
    const int* etype  = (const int*)d_in[34];

    float* ws = (float*)d_ws;
    float* R0 = ws;                        // L1: C fp32; L2: aggI planes; head: Ph
    float* R1 = ws + REGF;                 // L1: aggI planes; then x1 planes
    float* R2 = ws + 2 * REGF;             // aggO planes; head: fch + fpart
    float* p = ws + 3 * REGF;              // tail
    float* r1v = p;            p += 40000;
    float* r2v = p;            p += 40000;
    float* stk = p;            p += 409600;
    float* hfc = p;            p += 204800;
    float* x2c = p;            p += 409600;   // compact layer-2 output [2048][200]
    float* fsc = p;            p += 256;
    float* fsh = p;            p += 256;
    double* ds1 = (double*)p;  p += 512;
    double* ds2 = (double*)p;  p += 512;
    short* Wp = (short*)p;     p += (6 * WPLANE) / 2;
    int* map = (int*)p;        p += NENT;
    int* hist = (int*)p;       p += NENT;
    int* offs = (int*)p;       p += NENT + 4;
    int* cursor = (int*)p;     p += NENT;
    int* bsum = (int*)p;       p += 512;
    int4* recs = (int4*)p;     p += (size_t)NEDGE * 4;

    float* x1f = R0;                           // L1 gemm fp32 output (pre-BN)
    short* aggIh1 = (short*)R1, *aggIl1 = (short*)R1 + NDF;
    short* aggOh  = (short*)R2, *aggOl  = (short*)R2 + NDF;
    short* x1h = (short*)R1, *x1l = (short*)R1 + NDF;   // overwrites aggI planes
    short* aggIh2 = (short*)R0, *aggIl2 = (short*)R0 + NDF;
    _Float16* Ph  = (_Float16*)R0;
    _Float16* fch = (_Float16*)R2;
    float* fpart = R2 + 4200000;

    const size_t NEED = (size_t)(p - ws) * sizeof(float);
    if (ws_size < NEED) return;

    const int NBLK = (NENT + 255) / 256;   // 391
    const size_t DSBYTES = 512 * sizeof(double);

    // -------- CSR build + slot map --------
    hipMemsetAsync(hist, 0, NENT * sizeof(int), stream);
    hipMemsetAsync(map, 0xFF, NENT * sizeof(int), stream);      // -1
    edge_hist<<<1024, 256, 0, stream>>>(dst, hist);
    scan1<<<NBLK, 256, 0, stream>>>(hist, offs, bsum);
    scan2<<<1, 512, 0, stream>>>(bsum, NBLK);
    scan3<<<NBLK, 256, 0, stream>>>(hist, offs, bsum, cursor);
    edge_fill<<<1024, 256, 0, stream>>>(src, dst, etype, edge_norm, cursor, recs);
    build_map<<<(2 * NB + 255) / 256, 256, 0, stream>>>(subj, obj, map);

    dim3 gGemm((NENT + 127) / 128, 2);

    // -------- layer 1 (x input = fp32 init_embed) --------
    pack_w3<<<(3 * WPLANE + 255) / 256, 256, 0, stream>>>(w_in1, w_out1, w_loop1, lrel1, Wp);
    gather_nodes<0><<<(NENT + 3) / 4, 256, 0, stream>>>(
        init_embed, nullptr, nullptr, init_rel, offs, recs, aggIh1, aggIl1, aggOh, aggOl);
    hipMemsetAsync(ds1, 0, DSBYTES, stream);
    gemm_mfma<true><<<gGemm, 256, 0, stream>>>(
        aggIh1, aggIl1, aggOh, aggOl, init_embed, nullptr, nullptr,
        Wp, Wp + 3 * WPLANE, x1f, b1, nullptr, 1.f / 3.f, NENT, ds1, ds2);
    finalize_stats<<<1, 256, 0, stream>>>(ds1, ds2, gm1, be1, fsc, fsh, 200, (double)NENT);
    bn_tanh_split<<<4096, 256, 0, stream>>>(x1f, fsc, fsh, x1h, x1l, (long)NENT * 50);
    rel_mm<<<(40000 + 255) / 256, 256, 0, stream>>>(init_rel, w_rel1, r1v);

    // -------- layer 2 (x input = x1 planes hi+lo; compact output) --------
    pack_w3<<<(3 * WPLANE + 255) / 256, 256, 0, stream>>>(w_in2, w_out2, w_loop2, lrel2, Wp);
    gather_nodes<1><<<(NENT + 3) / 4, 256, 0, stream>>>(
        nullptr, x1h, x1l, r1v, offs, recs, aggIh2, aggIl2, aggOh, aggOl);
    hipMemsetAsync(ds1, 0, DSBYTES, stream);
    gemm_mfma<false><<<gGemm, 256, 0, stream>>>(
        aggIh2, aggIl2, aggOh, aggOl, nullptr, x1h, x1l,
        Wp, Wp + 3 * WPLANE, x2c, b2, map, 1.f / 3.f, NENT, ds1, ds2);
    finalize_stats<<<1, 256, 0, stream>>>(ds1, ds2, gm2, be2, fsc, fsh, 200, (double)NENT);
    bn_act_200<<<400, 256, 0, stream>>>(x2c, fsc, fsh, (long)2 * NB * 50, 0);
    rel_mm<<<(40000 + 255) / 256, 256, 0, stream>>>(r1v, w_rel2, r2v);

    // -------- ConvE head --------
    hipMemsetAsync(ds1, 0, DSBYTES, stream);
    build_stk<<<NB, 256, 0, stream>>>(x2c, r2v, subj, relidx, map, stk, ds1, ds2);
    finalize_stats<<<1, 256, 0, stream>>>(ds1, ds2, bn0_g, bn0_b, fsc, fsh, 1,
                                          (double)((long)NB * 400));
    hipMemsetAsync(ds1, 0, DSBYTES, stream);
    conv_fwd<<<NB, 256, 0, stream>>>(stk, conv_w, conv_b, fsc, fsh, Ph, ds1, ds2);
    finalize_stats<<<1, 256, 0, stream>>>(ds1, ds2, bn1_g, bn1_b, fsc, fsh, 200,
                                          (double)((long)NB * 196));
    bn1_relu_f16<<<4096, 256, 0, stream>>>(Ph, fsc, fsh);
    pack_fcw<<<(int)(((long)208 * FLATSZ + 255) / 256), 256, 0, stream>>>(fc_w, fch);
    fc_gemm<<<dim3(8, 98), 256, 0, stream>>>(Ph, fch, fpart);
    fc_reduce<<<800, 256, 0, stream>>>(fpart, fc_b, hfc);
    hipMemsetAsync(ds1, 0, DSBYTES, stream);
    colstats<<<4, 256, 0, stream>>>(hfc, NB, 256, ds1, ds2);
    finalize_stats<<<1, 256, 0, stream>>>(ds1, ds2, bn2_g, bn2_b, fsc, fsh, 200, (double)NB);
    bn_act_200<<<200, 256, 0, stream>>>(hfc, fsc, fsh, (long)NB * 50, 1);
    score_mm<<<dim3(NB / 16, NB / 16), 256, 0, stream>>>(hfc, x2c, obj, map, (float*)d_out);
}

// Round 13
// 1321.550 us; speedup vs baseline: 1.0739x; 1.0739x over previous
//
#include <hip/hip_runtime.h>

#define DIM 200
#define NENT 100000
#define NEDGE 1000000
#define EHALF 500000
#define NB 1024
#define NFILT 200
#define FLATSZ 39200

#define NDF ((size_t)NENT * DIM)
#define REGF ((size_t)20100000)
#define WPLANE (208 * 224)

typedef float floatx4 __attribute__((ext_vector_type(4)));
typedef short bf16x8 __attribute__((ext_vector_type(8)));
typedef short bf16x4 __attribute__((ext_vector_type(4)));
typedef _Float16 halfx8 __attribute__((ext_vector_type(8)));
typedef _Float16 halfx4 __attribute__((ext_vector_type(4)));

__device__ __forceinline__ void gAtomicAdd(float* p, float v) { unsafeAtomicAdd(p, v); }
__device__ __forceinline__ void gAtomicAdd(double* p, double v) { unsafeAtomicAdd(p, v); }

__device__ __forceinline__ short f2bf(float f) {
    union { float f; unsigned u; } v; v.f = f;
    unsigned r = v.u + 0x7fffu + ((v.u >> 16) & 1u);
    return (short)(r >> 16);
}
__device__ __forceinline__ float bf2f(short s) {
    union { float f; unsigned u; } v; v.u = ((unsigned)(unsigned short)s) << 16;
    return v.f;
}
__device__ __forceinline__ void split8(const floatx4& lo4, const floatx4& hi4,
                                       bf16x8& h, bf16x8& l) {
#pragma unroll
    for (int e = 0; e < 4; ++e) {
        short hh = f2bf(lo4[e]); h[e] = hh; l[e] = f2bf(lo4[e] - bf2f(hh));
        short hh2 = f2bf(hi4[e]); h[e + 4] = hh2; l[e + 4] = f2bf(hi4[e] - bf2f(hh2));
    }
}

// ---------------------------------------------------------------- CSR build
__global__ __launch_bounds__(256) void edge_hist(
    const int* __restrict__ dst, int* __restrict__ hist)
{
    int stride = gridDim.x * blockDim.x;
    for (int e = blockIdx.x * 256 + threadIdx.x; e < NEDGE; e += stride)
        atomicAdd(&hist[dst[e]], 1);
}

__global__ __launch_bounds__(256) void scan1(
    const int* __restrict__ hist, int* __restrict__ incl, int* __restrict__ bsum)
{
    __shared__ int sm[256];
    int i = blockIdx.x * 256 + threadIdx.x;
    int t = threadIdx.x;
    sm[t] = (i < NENT) ? hist[i] : 0;
    __syncthreads();
    for (int off = 1; off < 256; off <<= 1) {
        int v = (t >= off) ? sm[t - off] : 0;
        __syncthreads();
        sm[t] += v;
        __syncthreads();
    }
    if (i < NENT) incl[i] = sm[t];
    if (t == 255) bsum[blockIdx.x] = sm[255];
}

__global__ __launch_bounds__(512) void scan2(int* bsum, int nb)
{
    __shared__ int sm[512];
    int t = threadIdx.x;
    int v = (t < nb) ? bsum[t] : 0;
    sm[t] = v;
    __syncthreads();
    for (int off = 1; off < 512; off <<= 1) {
        int u = (t >= off) ? sm[t - off] : 0;
        __syncthreads();
        sm[t] += u;
        __syncthreads();
    }
    if (t < nb) bsum[t] = sm[t] - v;
}

__global__ __launch_bounds__(256) void scan3(
    const int* __restrict__ hist, int* __restrict__ offs,
    const int* __restrict__ bsum, int* __restrict__ cursor)
{
    int i = blockIdx.x * 256 + threadIdx.x;
    if (i < NENT) {
        int excl = offs[i] - hist[i] + bsum[blockIdx.x];
        offs[i] = excl;
        cursor[i] = excl;
    }
    if (i == 0) offs[NENT] = NEDGE;
}

__global__ __launch_bounds__(256) void edge_fill(
    const int* __restrict__ src, const int* __restrict__ dst,
    const int* __restrict__ etype, const float* __restrict__ enorm,
    int* __restrict__ cursor, int4* __restrict__ recs)
{
    int stride = gridDim.x * blockDim.x;
    for (int e = blockIdx.x * 256 + threadIdx.x; e < NEDGE; e += stride) {
        int pos = atomicAdd(&cursor[dst[e]], 1);
        recs[pos] = make_int4(src[e], etype[e] | ((e >= EHALF) ? 0x10000 : 0),
                              __float_as_int(enorm[e]), 0);
    }
}

__global__ __launch_bounds__(256) void build_map(
    const int* __restrict__ subj, const int* __restrict__ obj, int* __restrict__ map)
{
    int i = blockIdx.x * 256 + threadIdx.x;
    if (i < NB) map[subj[i]] = i;
    else if (i < 2 * NB) map[obj[i - NB]] = i;
}

// fp32 -> fp16 elementwise (x rows for the gathers)
__global__ __launch_bounds__(256) void to_f16(
    const float* __restrict__ X, _Float16* __restrict__ Y, long n4)
{
    long stride = (long)gridDim.x * blockDim.x;
    for (long i = (long)blockIdx.x * blockDim.x + threadIdx.x; i < n4; i += stride) {
        float4 v = ((const float4*)X)[i];
        halfx4 h;
        h[0] = (_Float16)v.x; h[1] = (_Float16)v.y;
        h[2] = (_Float16)v.z; h[3] = (_Float16)v.w;
        ((halfx4*)Y)[i] = h;
    }
}

// ---------------------------------------------------------------- gather (2-deep pipelined, fp16 x rows)
__global__ __launch_bounds__(256) void gather_nodes(
    const _Float16* __restrict__ x16, const float* __restrict__ r,
    const int* __restrict__ offs, const int4* __restrict__ recs,
    float* __restrict__ aggI, float* __restrict__ aggO)
{
    int node = blockIdx.x * 4 + (threadIdx.x >> 6);
    int lane = threadIdx.x & 63;
    if (node >= NENT) return;
    int beg = offs[node], end = offs[node + 1];
    bool act = lane < 50;
    int lane_c = min(lane, 49);
    const float4* rb = (const float4*)r;
    float4 aI = make_float4(0.f, 0.f, 0.f, 0.f);
    float4 aO = make_float4(0.f, 0.f, 0.f, 0.f);

    auto ld_x = [&](int s) -> float4 {
        halfx4 v = *(const halfx4*)&x16[(size_t)s * 200 + lane_c * 4];
        return make_float4((float)v[0], (float)v[1], (float)v[2], (float)v[3]);
    };

    if (beg < end) {
        int i1 = min(beg + 1, end - 1);
        int4 rcA = recs[beg];
        int4 rcB = recs[i1];
        float4 xvA = ld_x(rcA.x);
        float4 rvA = rb[(size_t)(rcA.y & 0xffff) * 50 + lane_c];
        for (int i = beg; i < end; ++i) {
            int i2 = min(i + 2, end - 1);
            int4 rcC = recs[i2];
            float4 xvB = ld_x(rcB.x);
            float4 rvB = rb[(size_t)(rcB.y & 0xffff) * 50 + lane_c];
            float w = __int_as_float(rcA.z);
            float wI = (rcA.y & 0x10000) ? 0.f : w;
            float wO = w - wI;
            float px = xvA.x * rvA.x, py = xvA.y * rvA.y,
                  pz = xvA.z * rvA.z, pw = xvA.w * rvA.w;
            aI.x += px * wI; aI.y += py * wI; aI.z += pz * wI; aI.w += pw * wI;
            aO.x += px * wO; aO.y += py * wO; aO.z += pz * wO; aO.w += pw * wO;
            rcA = rcB; rcB = rcC; xvA = xvB; rvA = rvB;
        }
    }
    if (act) {
        ((float4*)aggI)[(size_t)node * 50 + lane] = aI;
        ((float4*)aggO)[(size_t)node * 50 + lane] = aO;
    }
}

// ---------------------------------------------------------------- weight packing
__global__ __launch_bounds__(256) void pack_w3(
    const float* __restrict__ w0, const float* __restrict__ w1,
    const float* __restrict__ w2, const float* __restrict__ lrel,
    short* __restrict__ Wp)
{
    int i = blockIdx.x * 256 + threadIdx.x;
    if (i >= 3 * WPLANE) return;
    int seg = i / WPLANE, rem = i % WPLANE;
    int n = rem / 224, k = rem % 224;
    const float* W = (seg == 0) ? w0 : (seg == 1) ? w1 : w2;
    float v = (n < 200 && k < 200) ? W[k * 200 + n] : 0.f;
    if (seg == 2 && n < 200 && k < 200) v *= lrel[k];
    short hi = f2bf(v);
    Wp[i] = hi;
    Wp[i + 3 * WPLANE] = f2bf(v - bf2f(hi));
}

__global__ __launch_bounds__(256) void pack_fcw(
    const float* __restrict__ W, _Float16* __restrict__ Wt)
{
    long i = (long)blockIdx.x * 256 + threadIdx.x;
    if (i >= (long)208 * FLATSZ) return;
    int n = (int)(i / FLATSZ);
    Wt[i] = (n < 200) ? (_Float16)W[i] : (_Float16)0.f;
}

// ---------------------------------------------------------------- split-bf16 MFMA GEMM (round-10 structure)
// A0/A1 fp32 (split8 in-kernel); A2 fp32 (A2MODE=0) or fp16 (A2MODE=1).
template<int NF0, int NF, int A2MODE>
__device__ __forceinline__ void gemm_body(
    const float* A0, const float* A1,
    const float* __restrict__ A2f, const _Float16* __restrict__ A2h,
    const short* __restrict__ WpH, const short* __restrict__ WpL,
    float* C, const float* __restrict__ bias, const int* __restrict__ map,
    float alpha, int M, double* __restrict__ s1, double* __restrict__ s2,
    short* BsH, short* BsL, float* fsum, float* fsq)
{
    int t = threadIdx.x;
    int lane = t & 63, wave = t >> 6;
    int col16 = lane & 15, quad = lane >> 4;
    int row_base = blockIdx.x * 128 + wave * 32;
    if (t < 112) { fsum[t] = 0.f; fsq[t] = 0.f; }
    floatx4 acc[NF][2];
#pragma unroll
    for (int nf = 0; nf < NF; ++nf) { acc[nf][0] = (floatx4)0.f; acc[nf][1] = (floatx4)0.f; }
    int r0 = row_base + col16, r1 = row_base + 16 + col16;
    int r0c = min(r0, M - 1), r1c = min(r1, M - 1);
    const int rows4 = NF * 16 * 4;

    for (int kc = 0; kc < 21; ++kc) {
        int seg = kc / 7, c = kc - seg * 7, k0 = c * 32;
        const short* WH = WpH + seg * WPLANE;
        const short* WL = WpL + seg * WPLANE;
        for (int i = t; i < rows4; i += 256) {
            int nl = i >> 2, part = i & 3;
            int n = NF0 * 16 + nl;
            *(bf16x8*)&BsH[nl * 40 + part * 8] = *(const bf16x8*)&WH[n * 224 + k0 + part * 8];
            *(bf16x8*)&BsL[nl * 40 + part * 8] = *(const bf16x8*)&WL[n * 224 + k0 + part * 8];
        }
        __syncthreads();
        int koff = k0 + quad * 8;
        bf16x8 a0h, a0l, a1h, a1l;
        if (koff < 200) {
            size_t o0 = (size_t)r0c * 200 + koff, o1 = (size_t)r1c * 200 + koff;
            if (seg < 2) {
                const float* Ap = (seg == 0) ? A0 : A1;
                floatx4 l0 = *(const floatx4*)&Ap[o0];
                floatx4 h0 = *(const floatx4*)&Ap[o0 + 4];
                floatx4 l1 = *(const floatx4*)&Ap[o1];
                floatx4 h1 = *(const floatx4*)&Ap[o1 + 4];
                split8(l0, h0, a0h, a0l);
                split8(l1, h1, a1h, a1l);
            } else if (A2MODE == 0) {
                floatx4 l0 = *(const floatx4*)&A2f[o0];
                floatx4 h0 = *(const floatx4*)&A2f[o0 + 4];
                floatx4 l1 = *(const floatx4*)&A2f[o1];
                floatx4 h1 = *(const floatx4*)&A2f[o1 + 4];
                split8(l0, h0, a0h, a0l);
                split8(l1, h1, a1h, a1l);
            } else {
                halfx8 v0 = *(const halfx8*)&A2h[o0];
                halfx8 v1 = *(const halfx8*)&A2h[o1];
                floatx4 l0, h0, l1, h1;
#pragma unroll
                for (int e = 0; e < 4; ++e) {
                    l0[e] = (float)v0[e]; h0[e] = (float)v0[e + 4];
                    l1[e] = (float)v1[e]; h1[e] = (float)v1[e + 4];
                }
                split8(l0, h0, a0h, a0l);
                split8(l1, h1, a1h, a1l);
            }
        } else {
            a0h = (bf16x8)0; a0l = (bf16x8)0; a1h = (bf16x8)0; a1l = (bf16x8)0;
        }
#pragma unroll
        for (int nf = 0; nf < NF; ++nf) {
            bf16x8 bh = *(const bf16x8*)&BsH[(nf * 16 + col16) * 40 + quad * 8];
            bf16x8 bl = *(const bf16x8*)&BsL[(nf * 16 + col16) * 40 + quad * 8];
            acc[nf][0] = __builtin_amdgcn_mfma_f32_16x16x32_bf16(a0h, bh, acc[nf][0], 0, 0, 0);
            acc[nf][0] = __builtin_amdgcn_mfma_f32_16x16x32_bf16(a0h, bl, acc[nf][0], 0, 0, 0);
            acc[nf][0] = __builtin_amdgcn_mfma_f32_16x16x32_bf16(a0l, bh, acc[nf][0], 0, 0, 0);
            acc[nf][1] = __builtin_amdgcn_mfma_f32_16x16x32_bf16(a1h, bh, acc[nf][1], 0, 0, 0);
            acc[nf][1] = __builtin_amdgcn_mfma_f32_16x16x32_bf16(a1h, bl, acc[nf][1], 0, 0, 0);
            acc[nf][1] = __builtin_amdgcn_mfma_f32_16x16x32_bf16(a1l, bh, acc[nf][1], 0, 0, 0);
        }
        __syncthreads();
    }
    int slot[2][4];
    if (map) {
#pragma unroll
        for (int h = 0; h < 2; ++h)
#pragma unroll
            for (int j = 0; j < 4; ++j) {
                int rr = row_base + h * 16 + quad * 4 + j;
                slot[h][j] = (rr < M) ? map[rr] : -1;
            }
    }
#pragma unroll
    for (int nf = 0; nf < NF; ++nf) {
        int lc = nf * 16 + col16;
        int colg = NF0 * 16 + lc;
        if (colg >= 200) continue;
        float bv = bias[colg];
        float ls = 0.f, lq = 0.f;
#pragma unroll
        for (int h = 0; h < 2; ++h) {
            int rbase = row_base + h * 16 + quad * 4;
#pragma unroll
            for (int j = 0; j < 4; ++j) {
                int rr = rbase + j;
                if (rr < M) {
                    float v = acc[nf][h][j] * alpha + bv;
                    ls += v; lq += v * v;
                    if (!map) {
                        C[(size_t)rr * 200 + colg] = v;
                    } else {
                        int s = slot[h][j];
                        if (s >= 0) C[(size_t)s * 200 + colg] = v;
                    }
                }
            }
        }
        ls += __shfl_down(ls, 32); ls += __shfl_down(ls, 16);
        lq += __shfl_down(lq, 32); lq += __shfl_down(lq, 16);
        if (quad == 0) {
            atomicAdd(&fsum[lc], ls);
            atomicAdd(&fsq[lc], lq);
        }
    }
    __syncthreads();
    if (t < NF * 16) {
        int colg = NF0 * 16 + t;
        if (colg < 200) {
            gAtomicAdd(&s1[colg], (double)fsum[t]);
            gAtomicAdd(&s2[colg], (double)fsq[t]);
        }
    }
}

template<int A2MODE>
__global__ __launch_bounds__(256) void gemm_mfma(
    const float* A0, const float* A1,
    const float* A2f, const _Float16* A2h,
    const short* __restrict__ WpH, const short* __restrict__ WpL,
    float* C, const float* __restrict__ bias, const int* __restrict__ map,
    float alpha, int M, double* __restrict__ s1, double* __restrict__ s2)
{
    __shared__ short BsH[112 * 40];
    __shared__ short BsL[112 * 40];
    __shared__ float fsum[112];
    __shared__ float fsq[112];
    if (blockIdx.y == 0)
        gemm_body<0, 7, A2MODE>(A0, A1, A2f, A2h, WpH, WpL, C, bias, map,
                                alpha, M, s1, s2, BsH, BsL, fsum, fsq);
    else
        gemm_body<7, 6, A2MODE>(A0, A1, A2f, A2h, WpH, WpL, C, bias, map,
                                alpha, M, s1, s2, BsH, BsL, fsum, fsq);
}

// ---------------------------------------------------------------- fc MFMA GEMM body (fp16)
template<int NF0, int NF>
__device__ __forceinline__ void fc_gemm_body(
    const _Float16* __restrict__ Ph, const _Float16* __restrict__ Wt,
    float* __restrict__ part, int ky, _Float16* Bs)
{
    int t = threadIdx.x;
    int lane = t & 63, wave = t >> 6;
    int col16 = lane & 15, quad = lane >> 4;
    int row_base = blockIdx.x * 128 + wave * 32;
    int c0 = ky * 25;
    floatx4 acc[NF][2];
#pragma unroll
    for (int nf = 0; nf < NF; ++nf) { acc[nf][0] = (floatx4)0.f; acc[nf][1] = (floatx4)0.f; }
    int r0 = row_base + col16, r1 = row_base + 16 + col16;
    const int rows4 = NF * 16 * 4;

    for (int c = c0; c < c0 + 25; ++c) {
        int k0 = c * 32;
        for (int i = t; i < rows4; i += 256) {
            int nl = i >> 2, part_i = i & 3;
            int n = NF0 * 16 + nl;
            *(halfx8*)&Bs[nl * 40 + part_i * 8] =
                *(const halfx8*)&Wt[(size_t)n * FLATSZ + k0 + part_i * 8];
        }
        __syncthreads();
        int koff = k0 + quad * 8;
        halfx8 a0 = *(const halfx8*)&Ph[(size_t)r0 * FLATSZ + koff];
        halfx8 a1 = *(const halfx8*)&Ph[(size_t)r1 * FLATSZ + koff];
#pragma unroll
        for (int nf = 0; nf < NF; ++nf) {
            halfx8 b = *(const halfx8*)&Bs[(nf * 16 + col16) * 40 + quad * 8];
            acc[nf][0] = __builtin_amdgcn_mfma_f32_16x16x32_f16(a0, b, acc[nf][0], 0, 0, 0);
            acc[nf][1] = __builtin_amdgcn_mfma_f32_16x16x32_f16(a1, b, acc[nf][1], 0, 0, 0);
        }
        __syncthreads();
    }
    float* out = part + (size_t)ky * (NB * 200);
#pragma unroll
    for (int nf = 0; nf < NF; ++nf) {
        int colg = NF0 * 16 + nf * 16 + col16;
        if (colg >= 200) continue;
#pragma unroll
        for (int h = 0; h < 2; ++h) {
            int rbase = row_base + h * 16 + quad * 4;
#pragma unroll
            for (int j = 0; j < 4; ++j)
                out[(size_t)(rbase + j) * 200 + colg] = acc[nf][h][j];
        }
    }
}

__global__ __launch_bounds__(256) void fc_gemm(
    const _Float16* __restrict__ Ph, const _Float16* __restrict__ Wt,
    float* __restrict__ part)
{
    __shared__ _Float16 Bs[112 * 40];
    int ky = blockIdx.y >> 1;
    if ((blockIdx.y & 1) == 0)
        fc_gemm_body<0, 7>(Ph, Wt, part, ky, Bs);
    else
        fc_gemm_body<7, 6>(Ph, Wt, part, ky, Bs);
}

__global__ __launch_bounds__(256) void fc_reduce(
    const float* __restrict__ part, const float* __restrict__ bias,
    float* __restrict__ hfc)
{
    int i = blockIdx.x * 256 + threadIdx.x;
    float acc = bias[i % 200];
#pragma unroll
    for (int y = 0; y < 49; ++y) acc += part[(size_t)y * (NB * 200) + i];
    hfc[i] = acc;
}

// ---------------------------------------------------------------- stats / bn
__global__ __launch_bounds__(256) void colstats(
    const float* __restrict__ X, int M, int rpb,
    double* __restrict__ s1, double* __restrict__ s2)
{
    int c = threadIdx.x;
    if (c >= 200) return;
    int r0 = blockIdx.x * rpb;
    int r1 = min(r0 + rpb, M);
    float sum = 0.f, sq = 0.f;
    for (int rr = r0; rr < r1; ++rr) {
        float v = X[(size_t)rr * 200 + c];
        sum += v; sq += v * v;
    }
    gAtomicAdd(&s1[c], (double)sum);
    gAtomicAdd(&s2[c], (double)sq);
}

__global__ void finalize_stats(const double* __restrict__ s1, const double* __restrict__ s2,
                               const float* __restrict__ g, const float* __restrict__ bb,
                               float* __restrict__ sc, float* __restrict__ sh,
                               int ncols, double count)
{
    int c = threadIdx.x;
    if (c >= ncols) return;
    double m = s1[c] / count;
    double v = s2[c] / count - m * m;
    double scd = (double)g[c] / sqrt(v + 1e-5);
    sc[c] = (float)scd;
    sh[c] = (float)((double)bb[c] - m * scd);
}

// bn + tanh, fp32 in -> fp16 out (layer-1 x for gather + gemm A2)
__global__ __launch_bounds__(256) void bn_tanh_f16(
    const float* __restrict__ X, const float* __restrict__ sc,
    const float* __restrict__ sh, _Float16* __restrict__ Y, long n4)
{
    long stride = (long)gridDim.x * blockDim.x;
    for (long i = (long)blockIdx.x * blockDim.x + threadIdx.x; i < n4; i += stride) {
        int c4 = (int)(i % 50) * 4;
        float4 v = ((const float4*)X)[i];
        halfx4 h;
        h[0] = (_Float16)tanhf(v.x * sc[c4 + 0] + sh[c4 + 0]);
        h[1] = (_Float16)tanhf(v.y * sc[c4 + 1] + sh[c4 + 1]);
        h[2] = (_Float16)tanhf(v.z * sc[c4 + 2] + sh[c4 + 2]);
        h[3] = (_Float16)tanhf(v.w * sc[c4 + 3] + sh[c4 + 3]);
        ((halfx4*)Y)[i] = h;
    }
}

__global__ __launch_bounds__(256) void bn_act_200(
    float* __restrict__ X, const float* __restrict__ sc, const float* __restrict__ sh,
    long n4, int act)
{
    long stride = (long)gridDim.x * blockDim.x;
    for (long i = (long)blockIdx.x * blockDim.x + threadIdx.x; i < n4; i += stride) {
        int c4 = (int)(i % 50) * 4;
        float4 v = ((const float4*)X)[i];
        float a0 = v.x * sc[c4 + 0] + sh[c4 + 0];
        float a1 = v.y * sc[c4 + 1] + sh[c4 + 1];
        float a2 = v.z * sc[c4 + 2] + sh[c4 + 2];
        float a3 = v.w * sc[c4 + 3] + sh[c4 + 3];
        if (act == 0) { a0 = tanhf(a0); a1 = tanhf(a1); a2 = tanhf(a2); a3 = tanhf(a3); }
        else { a0 = fmaxf(a0, 0.f); a1 = fmaxf(a1, 0.f); a2 = fmaxf(a2, 0.f); a3 = fmaxf(a3, 0.f); }
        ((float4*)X)[i] = make_float4(a0, a1, a2, a3);
    }
}

__global__ __launch_bounds__(256) void rel_mm(
    const float* __restrict__ R, const float* __restrict__ W, float* __restrict__ O)
{
    int idx = blockIdx.x * blockDim.x + threadIdx.x;
    if (idx >= 200 * 200) return;
    int row = idx / 200, col = idx - row * 200;
    float acc = 0.f;
    for (int k = 0; k < 200; ++k) acc = fmaf(R[row * 200 + k], W[k * 200 + col], acc);
    O[idx] = acc;
}

__global__ __launch_bounds__(256) void build_stk(
    const float* __restrict__ x2c, const float* __restrict__ r2,
    const int* __restrict__ subj, const int* __restrict__ ridx,
    const int* __restrict__ map,
    float* __restrict__ stk, double* __restrict__ s1, double* __restrict__ s2)
{
    __shared__ float wsum[4], wsq[4];
    int b = blockIdx.x, t = threadIdx.x;
    const float* se = x2c + (size_t)map[subj[b]] * DIM;
    const float* re = r2 + (size_t)ridx[b] * DIM;
    float sum = 0.f, sq = 0.f;
    for (int i = t; i < 400; i += 256) {
        float v = (i < 200) ? se[i] : re[i - 200];
        stk[(size_t)b * 400 + i] = v;
        sum += v; sq += v * v;
    }
    for (int off = 32; off > 0; off >>= 1) {
        sum += __shfl_down(sum, off);
        sq  += __shfl_down(sq, off);
    }
    if ((t & 63) == 0) { wsum[t >> 6] = sum; wsq[t >> 6] = sq; }
    __syncthreads();
    if (t == 0) {
        float S = wsum[0] + wsum[1] + wsum[2] + wsum[3];
        float Q = wsq[0] + wsq[1] + wsq[2] + wsq[3];
        gAtomicAdd(&s1[0], (double)S);
        gAtomicAdd(&s2[0], (double)Q);
    }
}

__global__ __launch_bounds__(256) void conv_fwd(
    const float* __restrict__ stk, const float* __restrict__ conv_w,
    const float* __restrict__ conv_b, const float* __restrict__ sc0,
    const float* __restrict__ sh0, _Float16* __restrict__ Ph,
    double* __restrict__ s1, double* __restrict__ s2)
{
    __shared__ float img[400];
    __shared__ float wsm[9800];
    __shared__ float bsm[200];
    __shared__ float fsum[200];
    __shared__ float fsq[200];
    int b = blockIdx.x, t = threadIdx.x;
    float scale0 = sc0[0], shift0 = sh0[0];
    if (t < 200) { fsum[t] = 0.f; fsq[t] = 0.f; bsm[t] = conv_b[t]; }
    for (int i = t; i < 400; i += 256) img[i] = stk[(size_t)b * 400 + i] * scale0 + shift0;
    for (int i = t; i < 9800; i += 256) wsm[i] = conv_w[i];
    __syncthreads();
    for (int fy = t; fy < 2800; fy += 256) {
        int f = fy / 14, y = fy - (fy / 14) * 14;
        const float* wf = &wsm[f * 49];
        float acc[14];
        float bias = bsm[f];
#pragma unroll
        for (int xx = 0; xx < 14; ++xx) acc[xx] = bias;
#pragma unroll
        for (int i = 0; i < 7; ++i) {
            const float* rowp = &img[(y + i) * 20];
            float rv[20];
#pragma unroll
            for (int c = 0; c < 20; ++c) rv[c] = rowp[c];
#pragma unroll
            for (int j = 0; j < 7; ++j) {
                float wv = wf[i * 7 + j];
#pragma unroll
                for (int xx = 0; xx < 14; ++xx) acc[xx] = fmaf(rv[xx + j], wv, acc[xx]);
            }
        }
        float ls = 0.f, lq = 0.f;
        _Float16* pp = Ph + (size_t)b * FLATSZ + (size_t)f * 196 + y * 14;
#pragma unroll
        for (int xx = 0; xx < 14; ++xx) {
            float v = acc[xx];
            pp[xx] = (_Float16)v;
            ls += v; lq += v * v;
        }
        atomicAdd(&fsum[f], ls);
        atomicAdd(&fsq[f], lq);
    }
    __syncthreads();
    if (t < 200) {
        gAtomicAdd(&s1[t], (double)fsum[t]);
        gAtomicAdd(&s2[t], (double)fsq[t]);
    }
}

__global__ __launch_bounds__(256) void bn1_relu_f16(
    _Float16* __restrict__ Ph, const float* __restrict__ sc, const float* __restrict__ sh)
{
    long n4 = (long)NB * (FLATSZ / 4);
    long stride = (long)gridDim.x * blockDim.x;
    for (long i = (long)blockIdx.x * blockDim.x + threadIdx.x; i < n4; i += stride) {
        int k4 = (int)(i % (FLATSZ / 4));
        int f = k4 / 49;
        float s = sc[f], h = sh[f];
        halfx4 v = ((const halfx4*)Ph)[i];
#pragma unroll
        for (int e = 0; e < 4; ++e) {
            float x = (float)v[e];
            x = fmaxf(x * s + h, 0.f);
            v[e] = (_Float16)x;
        }
        ((halfx4*)Ph)[i] = v;
    }
}

__global__ __launch_bounds__(256) void score_mm(
    const float* __restrict__ Hn, const float* __restrict__ x2c,
    const int* __restrict__ obj, const int* __restrict__ map,
    float* __restrict__ out)
{
    __shared__ float Asm[16][17];
    __shared__ float Bsm[16][17];
    int tx = threadIdx.x & 15, ty = threadIdx.x >> 4;
    int row = blockIdx.y * 16 + ty;
    int col = blockIdx.x * 16 + tx;
    int oj = map[obj[blockIdx.x * 16 + ty]];
    float acc = 0.f;
    for (int k0 = 0; k0 < 200; k0 += 16) {
        int k = k0 + tx;
        Asm[ty][tx] = (k < 200) ? Hn[(size_t)row * 200 + k] : 0.f;
        Bsm[ty][tx] = (k < 200) ? x2c[(size_t)oj * 200 + k] : 0.f;
        __syncthreads();
#pragma unroll
        for (int kk = 0; kk < 16; ++kk) acc = fmaf(Asm[ty][kk], Bsm[tx][kk], acc);
        __syncthreads();
    }
    out[(size_t)row * NB + col] = 1.f / (1.f + expf(-acc));
}

// ---------------------------------------------------------------- driver
extern "C" void kernel_launch(void* const* d_in, const int* in_sizes, int n_in,
                              void* d_out, int out_size, void* d_ws, size_t ws_size,
                              hipStream_t stream)
{
    (void)in_sizes; (void)n_in; (void)out_size;
    const float* init_embed = (const float*)d_in[0];
    const float* init_rel   = (const float*)d_in[1];
    const float* edge_norm  = (const float*)d_in[2];
    const float* w_in1  = (const float*)d_in[3];
    const float* w_out1 = (const float*)d_in[4];
    const float* w_loop1= (const float*)d_in[5];
    const float* w_rel1 = (const float*)d_in[6];
    const float* lrel1  = (const float*)d_in[7];
    const float* b1     = (const float*)d_in[8];
    const float* gm1    = (const float*)d_in[9];
    const float* be1    = (const float*)d_in[10];
    const float* w_in2  = (const float*)d_in[11];
    const float* w_out2 = (const float*)d_in[12];
    const float* w_loop2= (const float*)d_in[13];
    const float* w_rel2 = (const float*)d_in[14];
    const float* lrel2  = (const float*)d_in[15];
    const float* b2     = (const float*)d_in[16];
    const float* gm2    = (const float*)d_in[17];
    const float* be2    = (const float*)d_in[18];
    const float* conv_w = (const float*)d_in[19];
    const float* conv_b = (const float*)d_in[20];
    const float* fc_w   = (const float*)d_in[21];
    const float* fc_b   = (const float*)d_in[22];
    const float* bn0_g  = (const float*)d_in[23];
    const float* bn0_b  = (const float*)d_in[24];
    const float* bn1_g  = (const float*)d_in[25];
    const float* bn1_b  = (const float*)d_in[26];
    const float* bn2_g  = (const float*)d_in[27];
    const float* bn2_b  = (const float*)d_in[28];
    const int* subj   = (const int*)d_in[29];
    const int* relidx = (const int*)d_in[30];
    const int* obj    = (const int*)d_in[31];
    const int* src    = (const int*)d_in[32];
    const int* dst    = (const int*)d_in[33];
    const int* etype  = (const int*)d_in[34];

    float* ws = (float*)d_ws;
    float* R0 = ws;                 // L1: ie16 then x1f (C); L2: aggI; head: Ph
    float* R1 = ws + REGF;          // L1: aggI; then x1_16 (fp16, 5M floats)
    float* R2 = ws + 2 * REGF;      // aggO; head: fch + fpart
    float* p = ws + 3 * REGF;       // tail
    float* r1v = p;            p += 40000;
    float* r2v = p;            p += 40000;
    float* stk = p;            p += 409600;
    float* hfc = p;            p += 204800;
    float* x2c = p;            p += 409600;
    float* fsc = p;            p += 256;
    float* fsh = p;            p += 256;
    double* ds1 = (double*)p;  p += 512;
    double* ds2 = (double*)p;  p += 512;
    short* Wp = (short*)p;     p += (6 * WPLANE) / 2;
    int* map = (int*)p;        p += NENT;
    int* hist = (int*)p;       p += NENT;
    int* offs = (int*)p;       p += NENT + 4;
    int* cursor = (int*)p;     p += NENT;
    int* bsum = (int*)p;       p += 512;
    int4* recs = (int4*)p;     p += (size_t)NEDGE * 4;

    _Float16* ie16 = (_Float16*)R0;   // fp16 init_embed (dead after L1 gather)
    float* x1f = R0;                  // L1 gemm C (clobbers ie16 -- ok)
    float* aggI1 = R1;
    float* aggO  = R2;
    _Float16* x1h = (_Float16*)R1;    // fp16 x1 (aggI1 dead after L1 gemm)
    float* aggI2 = R0;                // L2 aggI (x1f dead after bn_tanh_f16)
    _Float16* Ph  = (_Float16*)R0;
    _Float16* fch = (_Float16*)R2;
    float* fpart = R2 + 4200000;

    const size_t NEED = (size_t)(p - ws) * sizeof(float);
    if (ws_size < NEED) return;

    const int NBLK = (NENT + 255) / 256;
    const size_t DSBYTES = 512 * sizeof(double);

    // -------- CSR build + slot map --------
    hipMemsetAsync(hist, 0, NENT * sizeof(int), stream);
    hipMemsetAsync(map, 0xFF, NENT * sizeof(int), stream);
    edge_hist<<<1024, 256, 0, stream>>>(dst, hist);
    scan1<<<NBLK, 256, 0, stream>>>(hist, offs, bsum);
    scan2<<<1, 512, 0, stream>>>(bsum, NBLK);
    scan3<<<NBLK, 256, 0, stream>>>(hist, offs, bsum, cursor);
    edge_fill<<<1024, 256, 0, stream>>>(src, dst, etype, edge_norm, cursor, recs);
    build_map<<<(2 * NB + 255) / 256, 256, 0, stream>>>(subj, obj, map);

    dim3 gGemm((NENT + 127) / 128, 2);

    // -------- layer 1 --------
    pack_w3<<<(3 * WPLANE + 255) / 256, 256, 0, stream>>>(w_in1, w_out1, w_loop1, lrel1, Wp);
    to_f16<<<4096, 256, 0, stream>>>(init_embed, ie16, (long)NENT * 50);
    gather_nodes<<<(NENT + 3) / 4, 256, 0, stream>>>(ie16, init_rel, offs, recs,
                                                     aggI1, aggO);
    hipMemsetAsync(ds1, 0, DSBYTES, stream);
    gemm_mfma<0><<<gGemm, 256, 0, stream>>>(
        aggI1, aggO, init_embed, nullptr, Wp, Wp + 3 * WPLANE,
        x1f, b1, nullptr, 1.f / 3.f, NENT, ds1, ds2);
    finalize_stats<<<1, 256, 0, stream>>>(ds1, ds2, gm1, be1, fsc, fsh, 200, (double)NENT);
    bn_tanh_f16<<<4096, 256, 0, stream>>>(x1f, fsc, fsh, x1h, (long)NENT * 50);
    rel_mm<<<(40000 + 255) / 256, 256, 0, stream>>>(init_rel, w_rel1, r1v);

    // -------- layer 2 (fp16 x; compact output) --------
    pack_w3<<<(3 * WPLANE + 255) / 256, 256, 0, stream>>>(w_in2, w_out2, w_loop2, lrel2, Wp);
    gather_nodes<<<(NENT + 3) / 4, 256, 0, stream>>>(x1h, r1v, offs, recs,
                                                     aggI2, aggO);
    hipMemsetAsync(ds1, 0, DSBYTES, stream);
    gemm_mfma<1><<<gGemm, 256, 0, stream>>>(
        aggI2, aggO, nullptr, x1h, Wp, Wp + 3 * WPLANE,
        x2c, b2, map, 1.f / 3.f, NENT, ds1, ds2);
    finalize_stats<<<1, 256, 0, stream>>>(ds1, ds2, gm2, be2, fsc, fsh, 200, (double)NENT);
    bn_act_200<<<400, 256, 0, stream>>>(x2c, fsc, fsh, (long)2 * NB * 50, 0);
    rel_mm<<<(40000 + 255) / 256, 256, 0, stream>>>(r1v, w_rel2, r2v);

    // -------- ConvE head --------
    hipMemsetAsync(ds1, 0, DSBYTES, stream);
    build_stk<<<NB, 256, 0, stream>>>(x2c, r2v, subj, relidx, map, stk, ds1, ds2);
    finalize_stats<<<1, 256, 0, stream>>>(ds1, ds2, bn0_g, bn0_b, fsc, fsh, 1,
                                          (double)((long)NB * 400));
    hipMemsetAsync(ds1, 0, DSBYTES, stream);
    conv_fwd<<<NB, 256, 0, stream>>>(stk, conv_w, conv_b, fsc, fsh, Ph, ds1, ds2);
    finalize_stats<<<1, 256, 0, stream>>>(ds1, ds2, bn1_g, bn1_b, fsc, fsh, 200,
                                          (double)((long)NB * 196));
    bn1_relu_f16<<<4096, 256, 0, stream>>>(Ph, fsc, fsh);
    pack_fcw<<<(int)(((long)208 * FLATSZ + 255) / 256), 256, 0, stream>>>(fc_w, fch);
    fc_gemm<<<dim3(8, 98), 256, 0, stream>>>(Ph, fch, fpart);
    fc_reduce<<<800, 256, 0, stream>>>(fpart, fc_b, hfc);
    hipMemsetAsync(ds1, 0, DSBYTES, stream);
    colstats<<<4, 256, 0, stream>>>(hfc, NB, 256, ds1, ds2);
    finalize_stats<<<1, 256, 0, stream>>>(ds1, ds2, bn2_g, bn2_b, fsc, fsh, 200, (double)NB);
    bn_act_200<<<200, 256, 0, stream>>>(hfc, fsc, fsh, (long)NB * 50, 1);
    score_mm<<<dim3(NB / 16, NB / 16), 256, 0, stream>>>(hfc, x2c, obj, map, (float*)d_out);
}